// Round 2
// baseline (242.963 us; speedup 1.0000x reference)
//
#include <hip/hip_runtime.h>

typedef __bf16 bfvec8 __attribute__((ext_vector_type(8)));
typedef float f32x4 __attribute__((ext_vector_type(4)));
typedef unsigned short u16x8 __attribute__((ext_vector_type(8)));
typedef unsigned int u32;

constexpr int C_IN = 128, Wd = 56, Hd = 56, HW = 3136, K_OUT = 256, N_IMG = 32;
constexpr int KKTOT = 1152;      // 128*9
constexpr int WP = 58;           // padded H/W
constexpr size_t XP_ELEMS = (size_t)N_IMG * WP * WP * C_IN;   // 13,776,896
constexpr size_t XP_BYTES = XP_ELEMS * 2;                     // 27,553,792
constexpr size_t WT_ELEMS = (size_t)9 * 4 * 2 * 128 * 32;     // 294,912
constexpr size_t WS_NEED  = XP_BYTES + WT_ELEMS * 2;

__device__ inline unsigned short f2bf(float f) {
    union { float f; unsigned u; } v; v.f = f;
    unsigned u = v.u;
    u += 0x7fffu + ((u >> 16) & 1u);   // round-to-nearest-even
    return (unsigned short)(u >> 16);
}

__device__ inline void gld16(const void* g, void* l) {
    __builtin_amdgcn_global_load_lds(
        (const __attribute__((address_space(1))) u32*)g,
        (__attribute__((address_space(3))) u32*)l, 16, 0, 0);
}

// compiler memory fence (no instruction) — pins LDS/global ops vs barriers
#define CFENCE() asm volatile("" ::: "memory")

// ---- Pre-pass 1: x NCHW fp32 -> halo-padded NHWC bf16 ---------------------
__global__ __launch_bounds__(256) void xpose(const float* __restrict__ x,
                                             unsigned short* __restrict__ xp) {
    __shared__ unsigned short T[Wd * C_IN];   // 14336 B
    const int nb = blockIdx.x;                // n*56 + h
    const int n = nb / Hd, h = nb - n * Hd;
    const float* src = x + (size_t)n * C_IN * HW + h * Wd;
    #pragma unroll
    for (int k = 0; k < 7; ++k) {
        int idx = threadIdx.x + k * 256;      // float4 index 0..1791
        int c = idx / 14, w4 = idx - c * 14;
        const float4 v = *(const float4*)(src + (size_t)c * HW + w4 * 4);
        const int sw = (w4 & 15) * 8;         // (w>>2)&15 == w4 for w4<=13
        T[(w4 * 4 + 0) * C_IN + (c ^ sw)] = f2bf(v.x);
        T[(w4 * 4 + 1) * C_IN + (c ^ sw)] = f2bf(v.y);
        T[(w4 * 4 + 2) * C_IN + (c ^ sw)] = f2bf(v.z);
        T[(w4 * 4 + 3) * C_IN + (c ^ sw)] = f2bf(v.w);
    }
    __syncthreads();
    unsigned short* dst = xp + ((size_t)(n * WP + h + 1) * WP + 1) * C_IN;
    const u16x8* s8 = (const u16x8*)T;
    u16x8* d8 = (u16x8*)dst;
    #pragma unroll
    for (int k = 0; k < 4; ++k) {
        int idx = threadIdx.x + k * 256;
        if (idx < 896) {
            int w = idx >> 4, j8 = idx & 15;
            d8[idx] = s8[w * 16 + (j8 ^ ((w >> 2) & 15))];
        }
    }
}

// ---- Pre-pass 2: weight OIHW fp32 -> packed bf16 tiles --------------------
// wt linear index o = (((rs*4 + chunk)*2 + ntile)*128 + n)*32 + kk
__global__ __launch_bounds__(256) void wxform(const float* __restrict__ w,
                                              unsigned short* __restrict__ wt) {
    int o = blockIdx.x * 256 + threadIdx.x;
    int kk = o & 31, n = (o >> 5) & 127, nt = (o >> 12) & 1,
        ch = (o >> 13) & 3, rs = o >> 15;
    float v = w[(size_t)(nt * 128 + n) * KKTOT + (ch * 32 + kk) * 9 + rs];
    wt[o] = f2bf(v);
}

// ---- Main GEMM: double-buffered LDS + counted vmcnt (T3/T4-lite) ----------
// Per step k: barrier (WAR: everyone done reading buf being refilled) ->
// issue step k+1's 4 global_load_lds into buf^1 -> s_waitcnt vmcnt(4)
// (step k's loads done; k+1's stay IN FLIGHT over the MFMA phase) ->
// barrier -> frag reads + 16 MFMA from buf. Never drains vmcnt to 0 in loop.
__global__ __launch_bounds__(256) void conv_gemm(
    const unsigned short* __restrict__ xp, const unsigned short* __restrict__ wt,
    const float* __restrict__ bias, float* __restrict__ out)
{
    __shared__ __align__(16) unsigned short As[2][128 * 32];  // 2 x 8 KB
    __shared__ __align__(16) unsigned short Bs[2][128 * 32];

    const int tid = threadIdx.x;
    const int bx  = blockIdx.x;
    const int nt  = bx & 1;
    const int mtile = (bx >> 1) * 128;

    // swizzled chunk this lane must FETCH so that slot (r, tid&3) holds it
    const int cg8 = ((tid & 3) ^ ((tid >> 3) & 3)) * 8;   // halfword offset

    const unsigned short *gA0, *gA1;
    {
        int mrow = tid >> 2;
        int m = mtile + mrow;
        int ni = m / HW; int hw = m - ni * HW; int h = hw / Wd; int w = hw - h * Wd;
        gA0 = xp + ((size_t)(ni * WP + h + 1) * WP + (w + 1)) * C_IN + cg8;
        m += 64;
        ni = m / HW; hw = m - ni * HW; h = hw / Wd; w = hw - h * Wd;
        gA1 = xp + ((size_t)(ni * WP + h + 1) * WP + (w + 1)) * C_IN + cg8;
    }
    const size_t bbase = (size_t)(tid & 0xFC) * 8 + cg8;   // (n-row)*32 + swz chunk

    const int wave = tid >> 6, lane = tid & 63;
    const int wrow = (wave >> 1) * 64, wcol = (wave & 1) * 64;
    const int r16 = lane & 15, quad = lane >> 4;
    const int qsw = (quad ^ ((r16 >> 1) & 3)) * 8;   // swizzled read offset

    const f32x4 zero4 = {0.f, 0.f, 0.f, 0.f};
    f32x4 acc[4][4];
    #pragma unroll
    for (int i = 0; i < 4; ++i)
        #pragma unroll
        for (int j = 0; j < 4; ++j)
            acc[i][j] = zero4;

    // issue the 4 staging loads for `step` into buffer `buf`
    auto issue = [&](int step, int buf) {
        const int rs = step >> 2, ch = step & 3;
        const int dr = rs / 3 - 1, dc = rs % 3 - 1;
        const int aoff = (dr * WP + dc) * C_IN + ch * 32;        // wave-uniform
        const size_t boff = (size_t)(((rs * 4 + ch) * 2 + nt) * 4096) + bbase;
        gld16(gA0 + aoff, (void*)(As[buf] + tid * 8));
        gld16(gA1 + aoff, (void*)(As[buf] + 2048 + tid * 8));
        gld16(wt + boff,        (void*)(Bs[buf] + tid * 8));
        gld16(wt + boff + 2048, (void*)(Bs[buf] + 2048 + tid * 8));
    };

    issue(0, 0);                                  // prologue prefetch

    for (int step = 0; step < 36; ++step) {
        const int cur = step & 1;

        CFENCE(); __builtin_amdgcn_s_barrier(); CFENCE();   // WAR on buf cur^1
        const int nxt = (step < 35) ? step + 1 : 35;        // tail: redundant reload
        issue(nxt, cur ^ 1);
        asm volatile("s_waitcnt vmcnt(4)" ::: "memory");    // buf[cur] loads done
        CFENCE(); __builtin_amdgcn_s_barrier(); CFENCE();   // ...for ALL waves

        bfvec8 af[4], bf[4];
        #pragma unroll
        for (int mi = 0; mi < 4; ++mi)
            af[mi] = *(const bfvec8*)&As[cur][(wrow + mi * 16 + r16) * 32 + qsw];
        #pragma unroll
        for (int ni = 0; ni < 4; ++ni)
            bf[ni] = *(const bfvec8*)&Bs[cur][(wcol + ni * 16 + r16) * 32 + qsw];

        #pragma unroll
        for (int mi = 0; mi < 4; ++mi)
            #pragma unroll
            for (int ni = 0; ni < 4; ++ni)
                acc[mi][ni] = __builtin_amdgcn_mfma_f32_16x16x32_bf16(
                    af[mi], bf[ni], acc[mi][ni], 0, 0, 0);
    }

    // drain the redundant tail prefetch before wave exit (LDS dealloc safety)
    asm volatile("s_waitcnt vmcnt(0)" ::: "memory");

    // epilogue: D col=lane&15 -> k, row=quad*4+i -> m; i is m-consecutive ->
    // hwe-consecutive (3136%4==0, base%4==0) -> dwordx4 stores
    const int ntile = nt * 128;
    #pragma unroll
    for (int ni = 0; ni < 4; ++ni) {
        const int k = ntile + wcol + ni * 16 + r16;
        const float bb = bias[k];
        #pragma unroll
        for (int mi = 0; mi < 4; ++mi) {
            const int mb  = mtile + wrow + mi * 16 + quad * 4;
            const int ne  = mb / HW;
            const int hwe = mb - ne * HW;
            f32x4 v;
            #pragma unroll
            for (int i = 0; i < 4; ++i) v[i] = acc[mi][ni][i] + bb;
            *(f32x4*)(out + ((size_t)ne * K_OUT + k) * HW + hwe) = v;
        }
    }
}

extern "C" void kernel_launch(void* const* d_in, const int* in_sizes, int n_in,
                              void* d_out, int out_size, void* d_ws, size_t ws_size,
                              hipStream_t stream) {
    const float* x    = (const float*)d_in[0];
    const float* wgt  = (const float*)d_in[1];
    const float* bias = (const float*)d_in[2];
    float* out = (float*)d_out;

    unsigned short* xp = (unsigned short*)d_ws;
    unsigned short* wt = (unsigned short*)((char*)d_ws + XP_BYTES);

    hipMemsetAsync(d_ws, 0, XP_BYTES, stream);                       // halo zeros
    xpose<<<dim3(N_IMG * Hd), dim3(256), 0, stream>>>(x, xp);
    wxform<<<dim3((int)(WT_ELEMS / 256)), dim3(256), 0, stream>>>(wgt, wt);
    conv_gemm<<<dim3(1568), dim3(256), 0, stream>>>(xp, wt, bias, out);
}

// Round 3
// 215.143 us; speedup vs baseline: 1.1293x; 1.1293x over previous
//
#include <hip/hip_runtime.h>

typedef __bf16 bfvec8 __attribute__((ext_vector_type(8)));
typedef float f32x4 __attribute__((ext_vector_type(4)));
typedef unsigned short u16x8 __attribute__((ext_vector_type(8)));
typedef unsigned int u32;

constexpr int C_IN = 128, Wd = 56, Hd = 56, HW = 3136, K_OUT = 256, N_IMG = 32;
constexpr int KKTOT = 1152;      // 128*9
constexpr int WP = 58;           // padded H/W
constexpr size_t XP_ELEMS = (size_t)N_IMG * WP * WP * C_IN;   // 13,776,896
constexpr size_t XP_BYTES = XP_ELEMS * 2;                     // 27,553,792
constexpr size_t WT_ELEMS = (size_t)9 * 4 * 2 * 128 * 32;     // 294,912
constexpr size_t WS_NEED  = XP_BYTES + WT_ELEMS * 2;

__device__ inline unsigned short f2bf(float f) {
    union { float f; unsigned u; } v; v.f = f;
    unsigned u = v.u;
    u += 0x7fffu + ((u >> 16) & 1u);   // round-to-nearest-even
    return (unsigned short)(u >> 16);
}

__device__ inline void gld16(const void* g, void* l) {
    __builtin_amdgcn_global_load_lds(
        (const __attribute__((address_space(1))) u32*)g,
        (__attribute__((address_space(3))) u32*)l, 16, 0, 0);
}

// compiler memory fence (no instruction) — pins LDS/global ops vs barriers
#define CFENCE() asm volatile("" ::: "memory")

// ---- Pre-pass 1: x NCHW fp32 -> halo-padded NHWC bf16 ---------------------
__global__ __launch_bounds__(256) void xpose(const float* __restrict__ x,
                                             unsigned short* __restrict__ xp) {
    __shared__ unsigned short T[Wd * C_IN];   // 14336 B
    const int nb = blockIdx.x;                // n*56 + h
    const int n = nb / Hd, h = nb - n * Hd;
    const float* src = x + (size_t)n * C_IN * HW + h * Wd;
    #pragma unroll
    for (int k = 0; k < 7; ++k) {
        int idx = threadIdx.x + k * 256;      // float4 index 0..1791
        int c = idx / 14, w4 = idx - c * 14;
        const float4 v = *(const float4*)(src + (size_t)c * HW + w4 * 4);
        const int sw = (w4 & 15) * 8;         // (w>>2)&15 == w4 for w4<=13
        T[(w4 * 4 + 0) * C_IN + (c ^ sw)] = f2bf(v.x);
        T[(w4 * 4 + 1) * C_IN + (c ^ sw)] = f2bf(v.y);
        T[(w4 * 4 + 2) * C_IN + (c ^ sw)] = f2bf(v.z);
        T[(w4 * 4 + 3) * C_IN + (c ^ sw)] = f2bf(v.w);
    }
    __syncthreads();
    unsigned short* dst = xp + ((size_t)(n * WP + h + 1) * WP + 1) * C_IN;
    const u16x8* s8 = (const u16x8*)T;
    u16x8* d8 = (u16x8*)dst;
    #pragma unroll
    for (int k = 0; k < 4; ++k) {
        int idx = threadIdx.x + k * 256;
        if (idx < 896) {
            int w = idx >> 4, j8 = idx & 15;
            d8[idx] = s8[w * 16 + (j8 ^ ((w >> 2) & 15))];
        }
    }
}

// ---- Pre-pass 2: weight OIHW fp32 -> packed bf16 tiles --------------------
// wt linear index o = (((rs*4 + chunk)*2 + ntile)*128 + n)*32 + kk
__global__ __launch_bounds__(256) void wxform(const float* __restrict__ w,
                                              unsigned short* __restrict__ wt) {
    int o = blockIdx.x * 256 + threadIdx.x;
    int kk = o & 31, n = (o >> 5) & 127, nt = (o >> 12) & 1,
        ch = (o >> 13) & 3, rs = o >> 15;
    float v = w[(size_t)(nt * 128 + n) * KKTOT + (ch * 32 + kk) * 9 + rs];
    wt[o] = f2bf(v);
}

// ---- Main GEMM: ring-3 LDS, depth-2 prefetch, counted vmcnt, XCD swizzle --
// Fully unrolled 36-step loop: all per-step address math / buffer indices /
// wait counts are compile-time constants.  Per step k:
//   barrier                          (WAR: buf (k-1)%3 reads complete)
//   issue step k+2 into buf (k+2)%3  (== (k-1)%3)
//   s_waitcnt vmcnt(8)               (step k's 4 loads landed; 8 in flight)
//   barrier                          (all waves' step-k loads visible)
//   8 ds_read_b128 + 16 MFMA from buf k%3
// XCD swizzle: 1568 blocks = 8 x 196; each XCD gets 196 consecutive logical
// blocks = 98 consecutive mtiles -> ~3.4 MB xp slice, fits 4 MiB L2.
__global__ __launch_bounds__(256) void conv_gemm(
    const unsigned short* __restrict__ xp, const unsigned short* __restrict__ wt,
    const float* __restrict__ bias, float* __restrict__ out)
{
    __shared__ __align__(16) unsigned short As[3][128 * 32];  // 3 x 8 KB
    __shared__ __align__(16) unsigned short Bs[3][128 * 32];  // 3 x 8 KB

    const int tid = threadIdx.x;
    const int hbx = blockIdx.x;
    const int lbx = (hbx & 7) * 196 + (hbx >> 3);   // XCD-chunked, bijective
    const int nt  = lbx & 1;
    const int mtile = (lbx >> 1) * 128;

    // swizzled chunk this lane must FETCH so that slot (r, tid&3) holds it
    const int cg8 = ((tid & 3) ^ ((tid >> 3) & 3)) * 8;   // halfword offset

    const unsigned short *gA0, *gA1;
    {
        int mrow = tid >> 2;
        int m = mtile + mrow;
        int ni = m / HW; int hw = m - ni * HW; int h = hw / Wd; int w = hw - h * Wd;
        gA0 = xp + ((size_t)(ni * WP + h + 1) * WP + (w + 1)) * C_IN + cg8;
        m += 64;
        ni = m / HW; hw = m - ni * HW; h = hw / Wd; w = hw - h * Wd;
        gA1 = xp + ((size_t)(ni * WP + h + 1) * WP + (w + 1)) * C_IN + cg8;
    }
    // wt base for this block's n-tile + this lane's row/swizzle-chunk
    const unsigned short* gB = wt + (size_t)nt * 4096 + (size_t)(tid & 0xFC) * 8 + cg8;

    const int wave = tid >> 6, lane = tid & 63;
    const int wrow = (wave >> 1) * 64, wcol = (wave & 1) * 64;
    const int r16 = lane & 15, quad = lane >> 4;
    const int qsw = (quad ^ ((r16 >> 1) & 3)) * 8;   // swizzled read offset

    const f32x4 zero4 = {0.f, 0.f, 0.f, 0.f};
    f32x4 acc[4][4];
    #pragma unroll
    for (int i = 0; i < 4; ++i)
        #pragma unroll
        for (int j = 0; j < 4; ++j)
            acc[i][j] = zero4;

    // issue the 4 staging loads for `step` into ring buffer `buf`
    // (constexpr-foldable when step/buf are compile-time constants)
    auto issue = [&](int step, int buf) {
        const int rs = step >> 2, ch = step & 3;
        const int dr = rs / 3 - 1, dc = rs % 3 - 1;
        const int aoff = (dr * WP + dc) * C_IN + ch * 32;        // wave-uniform
        const size_t boff = (size_t)step * 8192;                 // (rs*4+ch)*2*4096
        gld16(gA0 + aoff, (void*)(As[buf] + tid * 8));
        gld16(gA1 + aoff, (void*)(As[buf] + 2048 + tid * 8));
        gld16(gB + boff,        (void*)(Bs[buf] + tid * 8));
        gld16(gB + boff + 2048, (void*)(Bs[buf] + 2048 + tid * 8));
    };

    issue(0, 0);                                  // prologue: depth-2 prefetch
    issue(1, 1);

    #pragma unroll
    for (int step = 0; step < 36; ++step) {
        const int cur = step % 3;

        CFENCE(); __builtin_amdgcn_s_barrier(); CFENCE();   // WAR on buf (step-1)%3
        if (step < 34) {
            issue(step + 2, (step + 2) % 3);
            asm volatile("s_waitcnt vmcnt(8)" ::: "memory");
        } else if (step == 34) {
            asm volatile("s_waitcnt vmcnt(4)" ::: "memory");
        } else {
            asm volatile("s_waitcnt vmcnt(0)" ::: "memory");
        }
        CFENCE(); __builtin_amdgcn_s_barrier(); CFENCE();   // step's loads visible

        bfvec8 af[4], bf[4];
        #pragma unroll
        for (int mi = 0; mi < 4; ++mi)
            af[mi] = *(const bfvec8*)&As[cur][(wrow + mi * 16 + r16) * 32 + qsw];
        #pragma unroll
        for (int ni = 0; ni < 4; ++ni)
            bf[ni] = *(const bfvec8*)&Bs[cur][(wcol + ni * 16 + r16) * 32 + qsw];

        #pragma unroll
        for (int mi = 0; mi < 4; ++mi)
            #pragma unroll
            for (int ni = 0; ni < 4; ++ni)
                acc[mi][ni] = __builtin_amdgcn_mfma_f32_16x16x32_bf16(
                    af[mi], bf[ni], acc[mi][ni], 0, 0, 0);
    }

    // epilogue: D col=lane&15 -> k, row=quad*4+i -> m; i is m-consecutive ->
    // hwe-consecutive (3136%4==0, base%4==0) -> dwordx4 stores
    const int ntile = nt * 128;
    #pragma unroll
    for (int ni = 0; ni < 4; ++ni) {
        const int k = ntile + wcol + ni * 16 + r16;
        const float bb = bias[k];
        #pragma unroll
        for (int mi = 0; mi < 4; ++mi) {
            const int mb  = mtile + wrow + mi * 16 + quad * 4;
            const int ne  = mb / HW;
            const int hwe = mb - ne * HW;
            f32x4 v;
            #pragma unroll
            for (int i = 0; i < 4; ++i) v[i] = acc[mi][ni][i] + bb;
            *(f32x4*)(out + ((size_t)ne * K_OUT + k) * HW + hwe) = v;
        }
    }
}

extern "C" void kernel_launch(void* const* d_in, const int* in_sizes, int n_in,
                              void* d_out, int out_size, void* d_ws, size_t ws_size,
                              hipStream_t stream) {
    const float* x    = (const float*)d_in[0];
    const float* wgt  = (const float*)d_in[1];
    const float* bias = (const float*)d_in[2];
    float* out = (float*)d_out;

    unsigned short* xp = (unsigned short*)d_ws;
    unsigned short* wt = (unsigned short*)((char*)d_ws + XP_BYTES);

    hipMemsetAsync(d_ws, 0, XP_BYTES, stream);                       // halo zeros
    xpose<<<dim3(N_IMG * Hd), dim3(256), 0, stream>>>(x, xp);
    wxform<<<dim3((int)(WT_ELEMS / 256)), dim3(256), 0, stream>>>(wgt, wt);
    conv_gemm<<<dim3(1568), dim3(256), 0, stream>>>(xp, wt, bias, out);
}